// Round 7
// baseline (23071.519 us; speedup 1.0000x reference)
//
#include <hip/hip_runtime.h>
#include <math.h>

// Problem constants
#define TT 256      // sequence length
#define BB 64       // batch
#define DD 300      // embedding dim
#define KP0 320     // layer-0 K padded to multiple of 32
#define HH 256      // hidden
#define KK 37       // CRF states
#define FH 1024     // 4*H
#define MTOT (TT*BB) // 16384 rows, time-major r = t*64 + b

typedef __attribute__((ext_vector_type(8))) short short8;  // 8 bf16 (4 VGPR) MFMA A/B frag
typedef __attribute__((ext_vector_type(4))) float f32x4;   // MFMA C/D frag

// ---------- bf16 helpers ----------
__device__ __forceinline__ float bf2f(unsigned short u) {
    union { float f; unsigned int i; } v; v.i = ((unsigned int)u) << 16; return v.f;
}
__device__ __forceinline__ unsigned short f2bf(float f) {
    union { float f; unsigned int i; } v; v.f = f;
    unsigned int i = v.i;
    unsigned int r = (i + 0x7FFFu + ((i >> 16) & 1u)) >> 16; // RNE
    return (unsigned short)r;
}
__device__ __forceinline__ float sigm(float x)   { return 1.0f / (1.0f + __expf(-x)); }
__device__ __forceinline__ float tanh_f(float x) { return 2.0f / (1.0f + __expf(-2.0f * x)) - 1.0f; }

// signed byte extract (compiler -> v_bfe_i32; products provably 24-bit -> v_mad_i32_i24)
__device__ __forceinline__ int sb0(int w) { return (w << 24) >> 24; }
__device__ __forceinline__ int sb1(int w) { return (w << 16) >> 24; }
__device__ __forceinline__ int sb2(int w) { return (w <<  8) >> 24; }
__device__ __forceinline__ int sb3(int w) { return  w        >> 24; }

// permute gate-major col (g*256+unit) -> interleaved (unit*4+g)
__device__ __forceinline__ int perm_col(int nn) { return ((nn & 255) << 2) | (nn >> 8); }

// ---------- prep: per-row quant step S[m][u*4+g] = max_k |Whh[m][(g*256+u)*256+k]| / 127 ----------
__global__ __launch_bounds__(64) void conv_scale(
    const float* __restrict__ w0f, const float* __restrict__ w0b,
    const float* __restrict__ w1f, const float* __restrict__ w1b,
    float* __restrict__ S)   // 4 x 1024
{
    const int m = blockIdx.x >> 10;
    const int r = blockIdx.x & 1023;          // r = g*256 + u
    const float* W = m == 0 ? w0f : m == 1 ? w0b : m == 2 ? w1f : w1b;
    const int t = threadIdx.x;
    float mx = 0.f;
    for (int k = t; k < HH; k += 64) mx = fmaxf(mx, fabsf(W[r * HH + k]));
    #pragma unroll
    for (int s = 32; s > 0; s >>= 1) mx = fmaxf(mx, __shfl_down(mx, s, 64));
    if (t == 0) {
        const int g = r >> 8, u = r & 255;
        S[m * 1024 + u * 4 + g] = fmaxf(mx, 1e-20f) / 127.0f;
    }
}

// ---------- prep: quantize Whh -> WQ int8, word[((kq*16+j)*256+u)*4+g] = 4 k (k0=kq*64+j*4) ----------
__global__ __launch_bounds__(256) void conv_wq(
    const float* __restrict__ w0f, const float* __restrict__ w0b,
    const float* __restrict__ w1f, const float* __restrict__ w1b,
    const float* __restrict__ S, unsigned int* __restrict__ WQ)
{
    const int idx = blockIdx.x * 256 + threadIdx.x;     // 0 .. 4*65536-1
    const int m = idx >> 16;
    const int r = idx & 65535;
    const float* W = m == 0 ? w0f : m == 1 ? w0b : m == 2 ? w1f : w1b;
    const int g  = r & 3;
    const int u  = (r >> 2) & 255;
    const int j  = (r >> 10) & 15;
    const int kq = r >> 14;
    const int k0 = kq * 64 + j * 4;
    const float s = S[m * 1024 + u * 4 + g];
    const float4 wv = *(const float4*)(W + (g * HH + u) * HH + k0);
    int q0 = (int)rintf(wv.x / s), q1 = (int)rintf(wv.y / s);
    int q2 = (int)rintf(wv.z / s), q3 = (int)rintf(wv.w / s);
    q0 = max(-127, min(127, q0)); q1 = max(-127, min(127, q1));
    q2 = max(-127, min(127, q2)); q3 = max(-127, min(127, q3));
    WQ[idx] = (unsigned int)(q0 & 0xff) | ((unsigned int)(q1 & 0xff) << 8) |
              ((unsigned int)(q2 & 0xff) << 16) | ((unsigned int)(q3 & 0xff) << 24);
}

// ---------- prep: WsbjT f32 [512][37] ----------
__global__ __launch_bounds__(256) void conv_wsbj(
    const float* __restrict__ Wsbj, float* __restrict__ WT)
{
    const int idx = blockIdx.x * 256 + threadIdx.x;
    if (idx >= 512 * KK) return;
    const int c = idx / KK, k = idx - c * KK;
    WT[idx] = Wsbj[k * 512 + c];
}

// ---------- prep: gather embedding rows -> Abf bf16 [16384][320] (zero-pad k>=300) ----------
__global__ __launch_bounds__(320) void conv_gather(
    const int* __restrict__ text, const float* __restrict__ emb,
    unsigned short* __restrict__ Abf)
{
    const int r = blockIdx.x;
    const int k = threadIdx.x;
    const int t = r >> 6, b = r & 63;
    const int idx = text[b * TT + t];
    Abf[r * KP0 + k] = (k < DD) ? f2bf(emb[(size_t)idx * DD + k]) : (unsigned short)0;
}

// ---------- prep: W f32 (rows x kin) -> bf16 (rows x kout), zero-pad ----------
__global__ __launch_bounds__(256) void conv_w(
    const float* __restrict__ src, unsigned short* __restrict__ dst,
    int kin, int kout, int total)
{
    const int idx = blockIdx.x * 256 + threadIdx.x;
    if (idx >= total) return;
    const int rr = idx / kout, k = idx - rr * kout;
    dst[idx] = (k < kin) ? f2bf(src[rr * kin + k]) : (unsigned short)0;
}

// ---------- MFMA GEMM: out = A(M x lda bf16) @ W(1024 x lda bf16)^T + bias ----------
// 128x128 tile, 256 threads (4 waves, each 64x64 = 4x4 MFMA_16x16x32_bf16).
// Staging via global_load_lds width=16 (linear LDS layout = lane order, no padding).
__global__ __launch_bounds__(256) void gemm_mfma(
    const unsigned short* __restrict__ A,
    const unsigned short* __restrict__ W,
    const float* __restrict__ bias,
    unsigned short* __restrict__ out,
    int lda)
{
    const int bm = blockIdx.x * 128;
    const int bn = blockIdx.y * 128;
    const int tid = threadIdx.x;
    const int lane = tid & 63;
    const int wave = tid >> 6;
    const int wm = (wave & 1) * 64;
    const int wn = (wave >> 1) * 64;

    __shared__ __align__(16) unsigned short As[128 * 32];  // [row][k] 8 KB
    __shared__ __align__(16) unsigned short Bs[128 * 32];  // [wrow][k] 8 KB

    f32x4 acc[4][4] = {};

    const int srow = tid >> 2;          // 0..63
    const int sk = (tid & 3) * 8;       // k element offset (16 B granules)

    const unsigned short* ga0 = A + (size_t)(bm + srow) * lda + sk;
    const unsigned short* ga1 = A + (size_t)(bm + srow + 64) * lda + sk;
    const unsigned short* gb0 = W + (size_t)(bn + srow) * lda + sk;
    const unsigned short* gb1 = W + (size_t)(bn + srow + 64) * lda + sk;

    unsigned short* lA0 = As + wave * 512;
    unsigned short* lA1 = As + 2048 + wave * 512;
    unsigned short* lB0 = Bs + wave * 512;
    unsigned short* lB1 = Bs + 2048 + wave * 512;

    const int kiters = lda >> 5;
    for (int kb = 0; kb < kiters; kb++) {
        const int k0 = kb * 32;
        __builtin_amdgcn_global_load_lds(
            (const __attribute__((address_space(1))) unsigned int*)(ga0 + k0),
            (__attribute__((address_space(3))) unsigned int*)lA0, 16, 0, 0);
        __builtin_amdgcn_global_load_lds(
            (const __attribute__((address_space(1))) unsigned int*)(ga1 + k0),
            (__attribute__((address_space(3))) unsigned int*)lA1, 16, 0, 0);
        __builtin_amdgcn_global_load_lds(
            (const __attribute__((address_space(1))) unsigned int*)(gb0 + k0),
            (__attribute__((address_space(3))) unsigned int*)lB0, 16, 0, 0);
        __builtin_amdgcn_global_load_lds(
            (const __attribute__((address_space(1))) unsigned int*)(gb1 + k0),
            (__attribute__((address_space(3))) unsigned int*)lB1, 16, 0, 0);
        __syncthreads();

        short8 af[4], bfr[4];
        #pragma unroll
        for (int i = 0; i < 4; i++) {
            af[i]  = *(const short8*)&As[(wm + i * 16 + (lane & 15)) * 32 + (lane >> 4) * 8];
            bfr[i] = *(const short8*)&Bs[(wn + i * 16 + (lane & 15)) * 32 + (lane >> 4) * 8];
        }
        #pragma unroll
        for (int i = 0; i < 4; i++)
            #pragma unroll
            for (int j = 0; j < 4; j++)
                acc[i][j] = __builtin_amdgcn_mfma_f32_16x16x32_bf16(af[i], bfr[j], acc[i][j], 0, 0, 0);
        __syncthreads();
    }

    // C/D: col = lane&15, row = (lane>>4)*4 + reg  [measured m89/m91]
    const int cn = lane & 15;
    const int cr = (lane >> 4) * 4;
    #pragma unroll
    for (int j = 0; j < 4; j++) {
        const int n = bn + wn + j * 16 + cn;
        const float bv = bias[n];
        const int pc = perm_col(n);
        #pragma unroll
        for (int i = 0; i < 4; i++) {
            #pragma unroll
            for (int r = 0; r < 4; r++) {
                const int m = bm + wm + i * 16 + cr + r;
                out[(size_t)m * FH + pc] = f2bf(acc[i][j][r] + bv);
            }
        }
    }
}

// ---------- LSTM recurrence: grid (64 batches, 2 dirs), 1024 threads ----------
// R6 found the weight stream L2-BW-bound (16.8 GB @ 42 B/cy/CU = the whole 12K cy/step).
// Fix: weights VGPR-RESIDENT as int8 (16 uint4 = 64 VGPRs/thread, per-row scale),
// h quantized to int8 (1/127) in LDS (broadcast reads), integer bfe+mad inner loop,
// exact int cross-kq reduction. No in-loop VMEM except the tiny zin read.
// (R5 lesson: no manual prefetch games on streamed weights — moot now, nothing streams.)
__global__ __launch_bounds__(1024) void lstm_kernel(
    const unsigned short* __restrict__ zin_f, const unsigned short* __restrict__ zin_b,
    const int* __restrict__ WQf, const int* __restrict__ WQb,
    const float* __restrict__ Sf, const float* __restrict__ Sb,
    unsigned short* __restrict__ h_out)  // (T,B,512) bf16; fwd cols [0:256), bwd [256:512)
{
    const int dir = blockIdx.y;
    const unsigned short* zin = dir ? zin_b : zin_f;
    const int*   WQ = dir ? WQb : WQf;
    const float* S  = dir ? Sb  : Sf;
    const int off = dir ? HH : 0;

    const int b = blockIdx.x;
    const int tid = threadIdx.x;
    const int u  = tid & 255;
    const int kq = tid >> 8;            // wave-uniform

    __shared__ __align__(16) unsigned char hq8[2][HH];  // int8 h, double-buffered
    __shared__ int4 red[3][HH];                          // cross-kq partial sums

    // resident weights: 16 uint4 = 64 k x 4 gates int8
    int4 wq[16];
    {
        const int4* wbase = (const int4*)WQ + kq * 16 * 256 + u;
        #pragma unroll
        for (int j = 0; j < 16; j++) wq[j] = wbase[j * 256];
    }

    float4 sc = make_float4(0.f, 0.f, 0.f, 0.f);
    if (kq == 0) {
        sc = *(const float4*)(S + 4 * u);
        const float inv127 = 1.0f / 127.0f;
        sc.x *= inv127; sc.y *= inv127; sc.z *= inv127; sc.w *= inv127;
    }
    float c = 0.0f;
    int cur = 0;
    if (tid < 128) ((unsigned int*)hq8)[tid] = 0u;   // zero both buffers
    __syncthreads();

    for (int ts = 0; ts < TT; ts++) {
        const int tt = dir ? (TT - 1 - ts) : ts;
        const int row = tt * BB + b;

        // h for this thread's k-range: 64 int8 = 4 x int4, wave-broadcast reads
        const int4* hw = (const int4*)&hq8[cur][kq * 64];
        int a0 = 0, a1 = 0, a2 = 0, a3 = 0;
        #pragma unroll
        for (int q4 = 0; q4 < 4; q4++) {
            const int4 hv = hw[q4];
            #pragma unroll
            for (int e = 0; e < 4; e++) {
                const int hwrd = e == 0 ? hv.x : e == 1 ? hv.y : e == 2 ? hv.z : hv.w;
                const int h0 = sb0(hwrd), h1 = sb1(hwrd), h2 = sb2(hwrd), h3 = sb3(hwrd);
                const int4 w = wq[q4 * 4 + e];
                a0 += h0 * sb0(w.x) + h1 * sb1(w.x) + h2 * sb2(w.x) + h3 * sb3(w.x);
                a1 += h0 * sb0(w.y) + h1 * sb1(w.y) + h2 * sb2(w.y) + h3 * sb3(w.y);
                a2 += h0 * sb0(w.z) + h1 * sb1(w.z) + h2 * sb2(w.z) + h3 * sb3(w.z);
                a3 += h0 * sb0(w.w) + h1 * sb1(w.w) + h2 * sb2(w.w) + h3 * sb3(w.w);
            }
        }

        if (kq) red[kq - 1][u] = make_int4(a0, a1, a2, a3);
        __syncthreads();

        if (kq == 0) {
            const int4 r0 = red[0][u], r1 = red[1][u], r2 = red[2][u];
            const int A0 = a0 + r0.x + r1.x + r2.x;
            const int A1 = a1 + r0.y + r1.y + r2.y;
            const int A2 = a2 + r0.z + r1.z + r2.z;
            const int A3 = a3 + r0.w + r1.w + r2.w;
            const ushort4 zv = *(const ushort4*)(zin + row * FH + 4 * u);
            const float zi  = (float)A0 * sc.x + bf2f(zv.x);
            const float zf_ = (float)A1 * sc.y + bf2f(zv.y);
            const float zg  = (float)A2 * sc.z + bf2f(zv.z);
            const float zo  = (float)A3 * sc.w + bf2f(zv.w);
            const float cc = sigm(zf_) * c + sigm(zi) * tanh_f(zg);
            c = cc;
            const float hh = sigm(zo) * tanh_f(cc);
            hq8[cur ^ 1][u] = (unsigned char)((int)rintf(hh * 127.0f));
            h_out[row * (2 * HH) + off + u] = f2bf(hh);
        }
        __syncthreads();
        cur ^= 1;
    }
}

// ---------- Emission: em = h1 @ WsbjT + b_sbj, (MTOT,37) f32 ----------
__global__ __launch_bounds__(256) void em_kernel(
    const unsigned short* __restrict__ h1, const float* __restrict__ WsbjT,
    const float* __restrict__ bsbj, float* __restrict__ em)
{
    const int o = blockIdx.x * 256 + threadIdx.x;
    if (o >= MTOT * KK) return;
    const int r = o / KK, k = o - r * KK;
    const unsigned short* hr = h1 + r * 512;
    float s = bsbj[k];
    #pragma unroll 4
    for (int cidx = 0; cidx < 512; cidx++) {
        s += bf2f(hr[cidx]) * WsbjT[cidx * KK + k];
    }
    em[o] = s;
}

// ---------- CRF: one block (1 wave) per batch ----------
__global__ __launch_bounds__(64) void crf_kernel(
    const int* __restrict__ text, const int* __restrict__ sbj,
    const float* __restrict__ em,
    const float* __restrict__ start_t, const float* __restrict__ end_t,
    const float* __restrict__ trans, float* __restrict__ accum)
{
    const int b = blockIdx.x;
    const int tid = threadIdx.x;
    __shared__ float tr[KK * KK];
    __shared__ float sc[2][KK];
    for (int x = tid; x < KK * KK; x += 64) tr[x] = trans[x];

    int cnt = 0;
    for (int t = tid; t < TT; t += 64) cnt += (text[b * TT + t] != 0) ? 1 : 0;
    #pragma unroll
    for (int s = 32; s > 0; s >>= 1) cnt += __shfl_down(cnt, s, 64);
    const int len = __shfl(cnt, 0, 64);

    __syncthreads();

    float part = 0.f;
    for (int t = tid; t < TT; t += 64) {
        if (t >= 1 && t < len) {
            const int tg = sbj[b * TT + t];
            const int tp = sbj[b * TT + t - 1];
            part += em[(t * BB + b) * KK + tg] + tr[tp * KK + tg];
        }
    }
    #pragma unroll
    for (int s = 32; s > 0; s >>= 1) part += __shfl_down(part, s, 64);

    if (tid < KK) sc[0][tid] = start_t[tid] + em[b * KK + tid];
    __syncthreads();
    int cur = 0;
    for (int t = 1; t < len; t++) {
        float nv = 0.f;
        if (tid < KK) {
            float mx = -1e30f;
            for (int k1 = 0; k1 < KK; k1++)
                mx = fmaxf(mx, sc[cur][k1] + tr[k1 * KK + tid]);
            float s = 0.f;
            for (int k1 = 0; k1 < KK; k1++)
                s += __expf(sc[cur][k1] + tr[k1 * KK + tid] - mx);
            nv = mx + __logf(s) + em[(t * BB + b) * KK + tid];
        }
        if (tid < KK) sc[cur ^ 1][tid] = nv;
        __syncthreads();
        cur ^= 1;
    }

    if (tid == 0) {
        const int tg0 = sbj[b * TT];
        const int tgl = sbj[b * TT + len - 1];
        const float num = start_t[tg0] + em[b * KK + tg0] + part + end_t[tgl];
        float mx = -1e30f;
        for (int k = 0; k < KK; k++) mx = fmaxf(mx, sc[cur][k] + end_t[k]);
        float s = 0.f;
        for (int k = 0; k < KK; k++) s += __expf(sc[cur][k] + end_t[k] - mx);
        const float logZ = mx + __logf(s);
        atomicAdd(&accum[0], num - logZ);
        atomicAdd(&accum[1], (float)len);
    }
}

__global__ void init_kernel(float* __restrict__ accum) {
    if (threadIdx.x < 2) accum[threadIdx.x] = 0.0f;
}
__global__ void final_kernel(const float* __restrict__ accum, float* __restrict__ out) {
    out[0] = -(accum[0] / accum[1]);
}

// ---------- launch ----------
extern "C" void kernel_launch(void* const* d_in, const int* in_sizes, int n_in,
                              void* d_out, int out_size, void* d_ws, size_t ws_size,
                              hipStream_t stream)
{
    (void)in_sizes; (void)n_in; (void)out_size; (void)ws_size;
    const int*   text  = (const int*)d_in[0];
    const int*   sbj   = (const int*)d_in[1];
    const float* emb   = (const float*)d_in[2];
    const float* Wih0f = (const float*)d_in[3];
    const float* Whh0f = (const float*)d_in[4];
    const float* b0f   = (const float*)d_in[5];
    const float* Wih0b = (const float*)d_in[6];
    const float* Whh0b = (const float*)d_in[7];
    const float* b0b   = (const float*)d_in[8];
    const float* Wih1f = (const float*)d_in[9];
    const float* Whh1f = (const float*)d_in[10];
    const float* b1f   = (const float*)d_in[11];
    const float* Wih1b = (const float*)d_in[12];
    const float* Whh1b = (const float*)d_in[13];
    const float* b1b   = (const float*)d_in[14];
    const float* Wsbj  = (const float*)d_in[15];
    const float* bsbj  = (const float*)d_in[16];
    const float* start_t = (const float*)d_in[17];
    const float* end_t   = (const float*)d_in[18];
    const float* trans   = (const float*)d_in[19];

    // workspace map (bytes), max ~102.84 MB. Overlaps (stream-ordered lifetimes):
    //   Wb0f/Wb0b in h0 region (dead before lstm0 writes h0)
    //   Abf, Wb1f/Wb1b in h1 region (dead before lstm1 writes h1)
    //   em reuses zf (dead after lstm1)
    char* ws = (char*)d_ws;
    unsigned short* zf   = (unsigned short*)(ws + 0);           // 32 MiB
    unsigned short* zb   = (unsigned short*)(ws + 33554432);    // 32 MiB
    unsigned short* h0   = (unsigned short*)(ws + 67108864);    // 16 MiB
    unsigned short* h1   = (unsigned short*)(ws + 83886080);    // 16 MiB
    unsigned short* Wb0f = (unsigned short*)(ws + 67108864);    // 1024x320 bf16
    unsigned short* Wb0b = (unsigned short*)(ws + 67764224);
    unsigned short* Abf  = (unsigned short*)(ws + 83886080);    // 16384x320 bf16 (10 MiB)
    unsigned short* Wb1f = (unsigned short*)(ws + 94371840);    // 1024x512 bf16
    unsigned short* Wb1b = (unsigned short*)(ws + 95420416);
    unsigned int*   WQ   = (unsigned int*)(ws + 100663296);     // 4 x 256 KiB int8 weights
    float*          Sq   = (float*)(ws + 101711872);            // 4 x 4 KiB scales
    float*        WsbjT  = (float*)(ws + 102760448);            // 76 KiB
    float*          acc  = (float*)(ws + 102836224);            // 8 B
    float*           em  = (float*)(ws + 0);                    // 2.4 MiB (over zf)
    float* out = (float*)d_out;

    const int* WQ0f = (const int*)(WQ + 0 * 65536);
    const int* WQ0b = (const int*)(WQ + 1 * 65536);
    const int* WQ1f = (const int*)(WQ + 2 * 65536);
    const int* WQ1b = (const int*)(WQ + 3 * 65536);
    const float* S0f = Sq + 0 * 1024;
    const float* S0b = Sq + 1 * 1024;
    const float* S1f = Sq + 2 * 1024;
    const float* S1b = Sq + 3 * 1024;

    init_kernel<<<1, 64, 0, stream>>>(acc);
    conv_scale<<<dim3(4096), 64, 0, stream>>>(Whh0f, Whh0b, Whh1f, Whh1b, Sq);
    conv_wq<<<dim3(1024), 256, 0, stream>>>(Whh0f, Whh0b, Whh1f, Whh1b, Sq, WQ);
    conv_wsbj<<<dim3(74), 256, 0, stream>>>(Wsbj, WsbjT);
    conv_gather<<<dim3(MTOT), 320, 0, stream>>>(text, emb, Abf);
    conv_w<<<dim3(1280), 256, 0, stream>>>(Wih0f, Wb0f, DD, KP0, 1024 * KP0);
    conv_w<<<dim3(1280), 256, 0, stream>>>(Wih0b, Wb0b, DD, KP0, 1024 * KP0);
    conv_w<<<dim3(2048), 256, 0, stream>>>(Wih1f, Wb1f, 512, 512, 1024 * 512);
    conv_w<<<dim3(2048), 256, 0, stream>>>(Wih1b, Wb1b, 512, 512, 1024 * 512);

    // layer 0 input projection (MFMA)
    gemm_mfma<<<dim3(128, 8), 256, 0, stream>>>(Abf, Wb0f, b0f, zf, KP0);
    gemm_mfma<<<dim3(128, 8), 256, 0, stream>>>(Abf, Wb0b, b0b, zb, KP0);
    lstm_kernel<<<dim3(BB, 2), 1024, 0, stream>>>(zf, zb, WQ0f, WQ0b, S0f, S0b, h0);
    // layer 1 input projection (MFMA)
    gemm_mfma<<<dim3(128, 8), 256, 0, stream>>>(h0, Wb1f, b1f, zf, 512);
    gemm_mfma<<<dim3(128, 8), 256, 0, stream>>>(h0, Wb1b, b1b, zb, 512);
    lstm_kernel<<<dim3(BB, 2), 1024, 0, stream>>>(zf, zb, WQ1f, WQ1b, S1f, S1b, h1);

    em_kernel<<<(MTOT * KK + 255) / 256, 256, 0, stream>>>(h1, WsbjT, bsbj, em);
    crf_kernel<<<BB, 64, 0, stream>>>(text, sbj, em, start_t, end_t, trans, acc);
    final_kernel<<<1, 1, 0, stream>>>(acc, out);
}

// Round 8
// 3026.252 us; speedup vs baseline: 7.6238x; 7.6238x over previous
//
#include <hip/hip_runtime.h>
#include <math.h>

// Problem constants
#define TT 256      // sequence length
#define BB 64       // batch
#define DD 300      // embedding dim
#define KP0 320     // layer-0 K padded to multiple of 32
#define HH 256      // hidden
#define KK 37       // CRF states
#define FH 1024     // 4*H
#define MTOT (TT*BB) // 16384 rows, time-major r = t*64 + b

typedef __attribute__((ext_vector_type(8))) short short8;  // 8 bf16 (4 VGPR) MFMA A/B frag
typedef __attribute__((ext_vector_type(4))) float f32x4;   // MFMA C/D frag

// ---------- bf16 helpers ----------
__device__ __forceinline__ float bf2f(unsigned short u) {
    union { float f; unsigned int i; } v; v.i = ((unsigned int)u) << 16; return v.f;
}
__device__ __forceinline__ unsigned short f2bf(float f) {
    union { float f; unsigned int i; } v; v.f = f;
    unsigned int i = v.i;
    unsigned int r = (i + 0x7FFFu + ((i >> 16) & 1u)) >> 16; // RNE
    return (unsigned short)r;
}
__device__ __forceinline__ float sigm(float x)   { return 1.0f / (1.0f + __expf(-x)); }
__device__ __forceinline__ float tanh_f(float x) { return 2.0f / (1.0f + __expf(-2.0f * x)) - 1.0f; }

// signed byte extract (compiler -> v_bfe_i32; products provably 24-bit -> v_mad_i32_i24)
__device__ __forceinline__ int sb0(int w) { return (w << 24) >> 24; }
__device__ __forceinline__ int sb1(int w) { return (w << 16) >> 24; }
__device__ __forceinline__ int sb2(int w) { return (w <<  8) >> 24; }
__device__ __forceinline__ int sb3(int w) { return  w        >> 24; }

// permute gate-major col (g*256+unit) -> interleaved (unit*4+g)
__device__ __forceinline__ int perm_col(int nn) { return ((nn & 255) << 2) | (nn >> 8); }

// ---------- prep: per-row quant step S[m][u*4+g] = max_k |Whh[m][(g*256+u)*256+k]| / 127 ----------
__global__ __launch_bounds__(64) void conv_scale(
    const float* __restrict__ w0f, const float* __restrict__ w0b,
    const float* __restrict__ w1f, const float* __restrict__ w1b,
    float* __restrict__ S)   // 4 x 1024
{
    const int m = blockIdx.x >> 10;
    const int r = blockIdx.x & 1023;          // r = g*256 + u
    const float* W = m == 0 ? w0f : m == 1 ? w0b : m == 2 ? w1f : w1b;
    const int t = threadIdx.x;
    float mx = 0.f;
    for (int k = t; k < HH; k += 64) mx = fmaxf(mx, fabsf(W[r * HH + k]));
    #pragma unroll
    for (int s = 32; s > 0; s >>= 1) mx = fmaxf(mx, __shfl_down(mx, s, 64));
    if (t == 0) {
        const int g = r >> 8, u = r & 255;
        S[m * 1024 + u * 4 + g] = fmaxf(mx, 1e-20f) / 127.0f;
    }
}

// ---------- prep: quantize Whh -> WQ int8, word[((kq*16+j)*256+u)*4+g] = 4 k (k0=kq*64+j*4) ----------
__global__ __launch_bounds__(256) void conv_wq(
    const float* __restrict__ w0f, const float* __restrict__ w0b,
    const float* __restrict__ w1f, const float* __restrict__ w1b,
    const float* __restrict__ S, unsigned int* __restrict__ WQ)
{
    const int idx = blockIdx.x * 256 + threadIdx.x;     // 0 .. 4*65536-1
    const int m = idx >> 16;
    const int r = idx & 65535;
    const float* W = m == 0 ? w0f : m == 1 ? w0b : m == 2 ? w1f : w1b;
    const int g  = r & 3;
    const int u  = (r >> 2) & 255;
    const int j  = (r >> 10) & 15;
    const int kq = r >> 14;
    const int k0 = kq * 64 + j * 4;
    const float s = S[m * 1024 + u * 4 + g];
    const float4 wv = *(const float4*)(W + (g * HH + u) * HH + k0);
    int q0 = (int)rintf(wv.x / s), q1 = (int)rintf(wv.y / s);
    int q2 = (int)rintf(wv.z / s), q3 = (int)rintf(wv.w / s);
    q0 = max(-127, min(127, q0)); q1 = max(-127, min(127, q1));
    q2 = max(-127, min(127, q2)); q3 = max(-127, min(127, q3));
    WQ[idx] = (unsigned int)(q0 & 0xff) | ((unsigned int)(q1 & 0xff) << 8) |
              ((unsigned int)(q2 & 0xff) << 16) | ((unsigned int)(q3 & 0xff) << 24);
}

// ---------- prep: WsbjT f32 [512][37] ----------
__global__ __launch_bounds__(256) void conv_wsbj(
    const float* __restrict__ Wsbj, float* __restrict__ WT)
{
    const int idx = blockIdx.x * 256 + threadIdx.x;
    if (idx >= 512 * KK) return;
    const int c = idx / KK, k = idx - c * KK;
    WT[idx] = Wsbj[k * 512 + c];
}

// ---------- prep: gather embedding rows -> Abf bf16 [16384][320] (zero-pad k>=300) ----------
__global__ __launch_bounds__(320) void conv_gather(
    const int* __restrict__ text, const float* __restrict__ emb,
    unsigned short* __restrict__ Abf)
{
    const int r = blockIdx.x;
    const int k = threadIdx.x;
    const int t = r >> 6, b = r & 63;
    const int idx = text[b * TT + t];
    Abf[r * KP0 + k] = (k < DD) ? f2bf(emb[(size_t)idx * DD + k]) : (unsigned short)0;
}

// ---------- prep: W f32 (rows x kin) -> bf16 (rows x kout), zero-pad ----------
__global__ __launch_bounds__(256) void conv_w(
    const float* __restrict__ src, unsigned short* __restrict__ dst,
    int kin, int kout, int total)
{
    const int idx = blockIdx.x * 256 + threadIdx.x;
    if (idx >= total) return;
    const int rr = idx / kout, k = idx - rr * kout;
    dst[idx] = (k < kin) ? f2bf(src[rr * kin + k]) : (unsigned short)0;
}

// ---------- MFMA GEMM: out = A(M x lda bf16) @ W(1024 x lda bf16)^T + bias ----------
// 128x128 tile, 256 threads (4 waves, each 64x64 = 4x4 MFMA_16x16x32_bf16).
// Staging via global_load_lds width=16 (linear LDS layout = lane order, no padding).
__global__ __launch_bounds__(256) void gemm_mfma(
    const unsigned short* __restrict__ A,
    const unsigned short* __restrict__ W,
    const float* __restrict__ bias,
    unsigned short* __restrict__ out,
    int lda)
{
    const int bm = blockIdx.x * 128;
    const int bn = blockIdx.y * 128;
    const int tid = threadIdx.x;
    const int lane = tid & 63;
    const int wave = tid >> 6;
    const int wm = (wave & 1) * 64;
    const int wn = (wave >> 1) * 64;

    __shared__ __align__(16) unsigned short As[128 * 32];  // [row][k] 8 KB
    __shared__ __align__(16) unsigned short Bs[128 * 32];  // [wrow][k] 8 KB

    f32x4 acc[4][4] = {};

    const int srow = tid >> 2;          // 0..63
    const int sk = (tid & 3) * 8;       // k element offset (16 B granules)

    const unsigned short* ga0 = A + (size_t)(bm + srow) * lda + sk;
    const unsigned short* ga1 = A + (size_t)(bm + srow + 64) * lda + sk;
    const unsigned short* gb0 = W + (size_t)(bn + srow) * lda + sk;
    const unsigned short* gb1 = W + (size_t)(bn + srow + 64) * lda + sk;

    unsigned short* lA0 = As + wave * 512;
    unsigned short* lA1 = As + 2048 + wave * 512;
    unsigned short* lB0 = Bs + wave * 512;
    unsigned short* lB1 = Bs + 2048 + wave * 512;

    const int kiters = lda >> 5;
    for (int kb = 0; kb < kiters; kb++) {
        const int k0 = kb * 32;
        __builtin_amdgcn_global_load_lds(
            (const __attribute__((address_space(1))) unsigned int*)(ga0 + k0),
            (__attribute__((address_space(3))) unsigned int*)lA0, 16, 0, 0);
        __builtin_amdgcn_global_load_lds(
            (const __attribute__((address_space(1))) unsigned int*)(ga1 + k0),
            (__attribute__((address_space(3))) unsigned int*)lA1, 16, 0, 0);
        __builtin_amdgcn_global_load_lds(
            (const __attribute__((address_space(1))) unsigned int*)(gb0 + k0),
            (__attribute__((address_space(3))) unsigned int*)lB0, 16, 0, 0);
        __builtin_amdgcn_global_load_lds(
            (const __attribute__((address_space(1))) unsigned int*)(gb1 + k0),
            (__attribute__((address_space(3))) unsigned int*)lB1, 16, 0, 0);
        __syncthreads();

        short8 af[4], bfr[4];
        #pragma unroll
        for (int i = 0; i < 4; i++) {
            af[i]  = *(const short8*)&As[(wm + i * 16 + (lane & 15)) * 32 + (lane >> 4) * 8];
            bfr[i] = *(const short8*)&Bs[(wn + i * 16 + (lane & 15)) * 32 + (lane >> 4) * 8];
        }
        #pragma unroll
        for (int i = 0; i < 4; i++)
            #pragma unroll
            for (int j = 0; j < 4; j++)
                acc[i][j] = __builtin_amdgcn_mfma_f32_16x16x32_bf16(af[i], bfr[j], acc[i][j], 0, 0, 0);
        __syncthreads();
    }

    // C/D: col = lane&15, row = (lane>>4)*4 + reg  [measured m89/m91]
    const int cn = lane & 15;
    const int cr = (lane >> 4) * 4;
    #pragma unroll
    for (int j = 0; j < 4; j++) {
        const int n = bn + wn + j * 16 + cn;
        const float bv = bias[n];
        const int pc = perm_col(n);
        #pragma unroll
        for (int i = 0; i < 4; i++) {
            #pragma unroll
            for (int r = 0; r < 4; r++) {
                const int m = bm + wm + i * 16 + cr + r;
                out[(size_t)m * FH + pc] = f2bf(acc[i][j][r] + bv);
            }
        }
    }
}

// ---------- LSTM recurrence: grid (64 batches, 2 dirs), 1024 threads ----------
// tid = kq*256 + u : thread covers 4 gates of unit u over k in [kq*64, kq*64+64).
// int8 weights STREAMED with the R4-proven schedule (loads inside #pragma unroll 4
// loop, coalesced 16 B/lane uint4) -> half the L2 bytes of the bf16 stream.
// h is int8 in LDS (broadcast dword reads); integer bfe+mad inner loop; exact
// int cross-kq reduction; per-row scales applied once in the kq==0 epilogue.
// LESSONS: R5 manual prefetch -> L2-miss explosion (37MB->10GB). R7 VGPR-resident
// wq[16] int4 array -> compiler SPILLED to scratch (VGPR_Count 64, 20GB traffic).
// Do not re-introduce either; >~32-reg per-thread arrays at 16 waves = spill trap.
__global__ __launch_bounds__(1024) void lstm_kernel(
    const unsigned short* __restrict__ zin_f, const unsigned short* __restrict__ zin_b,
    const int* __restrict__ WQf, const int* __restrict__ WQb,
    const float* __restrict__ Sf, const float* __restrict__ Sb,
    unsigned short* __restrict__ h_out)  // (T,B,512) bf16; fwd cols [0:256), bwd [256:512)
{
    const int dir = blockIdx.y;
    const unsigned short* zin = dir ? zin_b : zin_f;
    const int*   WQ = dir ? WQb : WQf;
    const float* S  = dir ? Sb  : Sf;
    const int off = dir ? HH : 0;

    const int b = blockIdx.x;
    const int tid = threadIdx.x;
    const int u  = tid & 255;
    const int kq = tid >> 8;            // wave-uniform

    __shared__ __align__(16) unsigned char hq8[2][HH];  // int8 h, double-buffered
    __shared__ int4 red[3][HH];                          // cross-kq partial sums

    // uint4 stream base: uint4 index ((kq*16 + j)*256 + u); component g holds 4 k's
    const int4* wp = (const int4*)WQ + kq * 16 * 256 + u;

    float4 sc = make_float4(0.f, 0.f, 0.f, 0.f);
    if (kq == 0) {
        sc = *(const float4*)(S + 4 * u);
        const float inv127 = 1.0f / 127.0f;
        sc.x *= inv127; sc.y *= inv127; sc.z *= inv127; sc.w *= inv127;
    }
    float c = 0.0f;
    int cur = 0;
    if (tid < 128) ((unsigned int*)hq8)[tid] = 0u;   // zero both buffers
    __syncthreads();

    for (int ts = 0; ts < TT; ts++) {
        const int tt = dir ? (TT - 1 - ts) : ts;
        const int row = tt * BB + b;

        const unsigned int* hw = (const unsigned int*)&hq8[cur][kq * 64];
        int a0 = 0, a1 = 0, a2 = 0, a3 = 0;
        #pragma unroll 4
        for (int j = 0; j < 16; j++) {
            const int hwrd = (int)hw[j];           // 4 int8 h, LDS broadcast
            const int4 w = wp[j * 256];            // 4 k x 4 gates int8, 16 B/lane
            const int h0 = sb0(hwrd), h1 = sb1(hwrd), h2 = sb2(hwrd), h3 = sb3(hwrd);
            a0 += h0 * sb0(w.x) + h1 * sb1(w.x) + h2 * sb2(w.x) + h3 * sb3(w.x);
            a1 += h0 * sb0(w.y) + h1 * sb1(w.y) + h2 * sb2(w.y) + h3 * sb3(w.y);
            a2 += h0 * sb0(w.z) + h1 * sb1(w.z) + h2 * sb2(w.z) + h3 * sb3(w.z);
            a3 += h0 * sb0(w.w) + h1 * sb1(w.w) + h2 * sb2(w.w) + h3 * sb3(w.w);
        }

        if (kq) red[kq - 1][u] = make_int4(a0, a1, a2, a3);
        __syncthreads();

        if (kq == 0) {
            const int4 r0 = red[0][u], r1 = red[1][u], r2 = red[2][u];
            const int A0 = a0 + r0.x + r1.x + r2.x;
            const int A1 = a1 + r0.y + r1.y + r2.y;
            const int A2 = a2 + r0.z + r1.z + r2.z;
            const int A3 = a3 + r0.w + r1.w + r2.w;
            const ushort4 zv = *(const ushort4*)(zin + row * FH + 4 * u);
            const float zi  = (float)A0 * sc.x + bf2f(zv.x);
            const float zf_ = (float)A1 * sc.y + bf2f(zv.y);
            const float zg  = (float)A2 * sc.z + bf2f(zv.z);
            const float zo  = (float)A3 * sc.w + bf2f(zv.w);
            const float cc = sigm(zf_) * c + sigm(zi) * tanh_f(zg);
            c = cc;
            const float hh = sigm(zo) * tanh_f(cc);
            hq8[cur ^ 1][u] = (unsigned char)((int)rintf(hh * 127.0f));
            h_out[row * (2 * HH) + off + u] = f2bf(hh);
        }
        __syncthreads();
        cur ^= 1;
    }
}

// ---------- Emission: em = h1 @ WsbjT + b_sbj, (MTOT,37) f32 ----------
__global__ __launch_bounds__(256) void em_kernel(
    const unsigned short* __restrict__ h1, const float* __restrict__ WsbjT,
    const float* __restrict__ bsbj, float* __restrict__ em)
{
    const int o = blockIdx.x * 256 + threadIdx.x;
    if (o >= MTOT * KK) return;
    const int r = o / KK, k = o - r * KK;
    const unsigned short* hr = h1 + r * 512;
    float s = bsbj[k];
    #pragma unroll 4
    for (int cidx = 0; cidx < 512; cidx++) {
        s += bf2f(hr[cidx]) * WsbjT[cidx * KK + k];
    }
    em[o] = s;
}

// ---------- CRF: one block (1 wave) per batch ----------
__global__ __launch_bounds__(64) void crf_kernel(
    const int* __restrict__ text, const int* __restrict__ sbj,
    const float* __restrict__ em,
    const float* __restrict__ start_t, const float* __restrict__ end_t,
    const float* __restrict__ trans, float* __restrict__ accum)
{
    const int b = blockIdx.x;
    const int tid = threadIdx.x;
    __shared__ float tr[KK * KK];
    __shared__ float sc[2][KK];
    for (int x = tid; x < KK * KK; x += 64) tr[x] = trans[x];

    int cnt = 0;
    for (int t = tid; t < TT; t += 64) cnt += (text[b * TT + t] != 0) ? 1 : 0;
    #pragma unroll
    for (int s = 32; s > 0; s >>= 1) cnt += __shfl_down(cnt, s, 64);
    const int len = __shfl(cnt, 0, 64);

    __syncthreads();

    float part = 0.f;
    for (int t = tid; t < TT; t += 64) {
        if (t >= 1 && t < len) {
            const int tg = sbj[b * TT + t];
            const int tp = sbj[b * TT + t - 1];
            part += em[(t * BB + b) * KK + tg] + tr[tp * KK + tg];
        }
    }
    #pragma unroll
    for (int s = 32; s > 0; s >>= 1) part += __shfl_down(part, s, 64);

    if (tid < KK) sc[0][tid] = start_t[tid] + em[b * KK + tid];
    __syncthreads();
    int cur = 0;
    for (int t = 1; t < len; t++) {
        float nv = 0.f;
        if (tid < KK) {
            float mx = -1e30f;
            for (int k1 = 0; k1 < KK; k1++)
                mx = fmaxf(mx, sc[cur][k1] + tr[k1 * KK + tid]);
            float s = 0.f;
            for (int k1 = 0; k1 < KK; k1++)
                s += __expf(sc[cur][k1] + tr[k1 * KK + tid] - mx);
            nv = mx + __logf(s) + em[(t * BB + b) * KK + tid];
        }
        if (tid < KK) sc[cur ^ 1][tid] = nv;
        __syncthreads();
        cur ^= 1;
    }

    if (tid == 0) {
        const int tg0 = sbj[b * TT];
        const int tgl = sbj[b * TT + len - 1];
        const float num = start_t[tg0] + em[b * KK + tg0] + part + end_t[tgl];
        float mx = -1e30f;
        for (int k = 0; k < KK; k++) mx = fmaxf(mx, sc[cur][k] + end_t[k]);
        float s = 0.f;
        for (int k = 0; k < KK; k++) s += __expf(sc[cur][k] + end_t[k] - mx);
        const float logZ = mx + __logf(s);
        atomicAdd(&accum[0], num - logZ);
        atomicAdd(&accum[1], (float)len);
    }
}

__global__ void init_kernel(float* __restrict__ accum) {
    if (threadIdx.x < 2) accum[threadIdx.x] = 0.0f;
}
__global__ void final_kernel(const float* __restrict__ accum, float* __restrict__ out) {
    out[0] = -(accum[0] / accum[1]);
}

// ---------- launch ----------
extern "C" void kernel_launch(void* const* d_in, const int* in_sizes, int n_in,
                              void* d_out, int out_size, void* d_ws, size_t ws_size,
                              hipStream_t stream)
{
    (void)in_sizes; (void)n_in; (void)out_size; (void)ws_size;
    const int*   text  = (const int*)d_in[0];
    const int*   sbj   = (const int*)d_in[1];
    const float* emb   = (const float*)d_in[2];
    const float* Wih0f = (const float*)d_in[3];
    const float* Whh0f = (const float*)d_in[4];
    const float* b0f   = (const float*)d_in[5];
    const float* Wih0b = (const float*)d_in[6];
    const float* Whh0b = (const float*)d_in[7];
    const float* b0b   = (const float*)d_in[8];
    const float* Wih1f = (const float*)d_in[9];
    const float* Whh1f = (const float*)d_in[10];
    const float* b1f   = (const float*)d_in[11];
    const float* Wih1b = (const float*)d_in[12];
    const float* Whh1b = (const float*)d_in[13];
    const float* b1b   = (const float*)d_in[14];
    const float* Wsbj  = (const float*)d_in[15];
    const float* bsbj  = (const float*)d_in[16];
    const float* start_t = (const float*)d_in[17];
    const float* end_t   = (const float*)d_in[18];
    const float* trans   = (const float*)d_in[19];

    // workspace map (bytes), max ~102.84 MB. Overlaps (stream-ordered lifetimes):
    //   Wb0f/Wb0b in h0 region (dead before lstm0 writes h0)
    //   Abf, Wb1f/Wb1b in h1 region (dead before lstm1 writes h1)
    //   em reuses zf (dead after lstm1)
    char* ws = (char*)d_ws;
    unsigned short* zf   = (unsigned short*)(ws + 0);           // 32 MiB
    unsigned short* zb   = (unsigned short*)(ws + 33554432);    // 32 MiB
    unsigned short* h0   = (unsigned short*)(ws + 67108864);    // 16 MiB
    unsigned short* h1   = (unsigned short*)(ws + 83886080);    // 16 MiB
    unsigned short* Wb0f = (unsigned short*)(ws + 67108864);    // 1024x320 bf16
    unsigned short* Wb0b = (unsigned short*)(ws + 67764224);
    unsigned short* Abf  = (unsigned short*)(ws + 83886080);    // 16384x320 bf16 (10 MiB)
    unsigned short* Wb1f = (unsigned short*)(ws + 94371840);    // 1024x512 bf16
    unsigned short* Wb1b = (unsigned short*)(ws + 95420416);
    unsigned int*   WQ   = (unsigned int*)(ws + 100663296);     // 4 x 256 KiB int8 weights
    float*          Sq   = (float*)(ws + 101711872);            // 4 x 4 KiB scales
    float*        WsbjT  = (float*)(ws + 102760448);            // 76 KiB
    float*          acc  = (float*)(ws + 102836224);            // 8 B
    float*           em  = (float*)(ws + 0);                    // 2.4 MiB (over zf)
    float* out = (float*)d_out;

    const int* WQ0f = (const int*)(WQ + 0 * 65536);
    const int* WQ0b = (const int*)(WQ + 1 * 65536);
    const int* WQ1f = (const int*)(WQ + 2 * 65536);
    const int* WQ1b = (const int*)(WQ + 3 * 65536);
    const float* S0f = Sq + 0 * 1024;
    const float* S0b = Sq + 1 * 1024;
    const float* S1f = Sq + 2 * 1024;
    const float* S1b = Sq + 3 * 1024;

    init_kernel<<<1, 64, 0, stream>>>(acc);
    conv_scale<<<dim3(4096), 64, 0, stream>>>(Whh0f, Whh0b, Whh1f, Whh1b, Sq);
    conv_wq<<<dim3(1024), 256, 0, stream>>>(Whh0f, Whh0b, Whh1f, Whh1b, Sq, WQ);
    conv_wsbj<<<dim3(74), 256, 0, stream>>>(Wsbj, WsbjT);
    conv_gather<<<dim3(MTOT), 320, 0, stream>>>(text, emb, Abf);
    conv_w<<<dim3(1280), 256, 0, stream>>>(Wih0f, Wb0f, DD, KP0, 1024 * KP0);
    conv_w<<<dim3(1280), 256, 0, stream>>>(Wih0b, Wb0b, DD, KP0, 1024 * KP0);
    conv_w<<<dim3(2048), 256, 0, stream>>>(Wih1f, Wb1f, 512, 512, 1024 * 512);
    conv_w<<<dim3(2048), 256, 0, stream>>>(Wih1b, Wb1b, 512, 512, 1024 * 512);

    // layer 0 input projection (MFMA)
    gemm_mfma<<<dim3(128, 8), 256, 0, stream>>>(Abf, Wb0f, b0f, zf, KP0);
    gemm_mfma<<<dim3(128, 8), 256, 0, stream>>>(Abf, Wb0b, b0b, zb, KP0);
    lstm_kernel<<<dim3(BB, 2), 1024, 0, stream>>>(zf, zb, WQ0f, WQ0b, S0f, S0b, h0);
    // layer 1 input projection (MFMA)
    gemm_mfma<<<dim3(128, 8), 256, 0, stream>>>(h0, Wb1f, b1f, zf, 512);
    gemm_mfma<<<dim3(128, 8), 256, 0, stream>>>(h0, Wb1b, b1b, zb, 512);
    lstm_kernel<<<dim3(BB, 2), 1024, 0, stream>>>(zf, zb, WQ1f, WQ1b, S1f, S1b, h1);

    em_kernel<<<(MTOT * KK + 255) / 256, 256, 0, stream>>>(h1, WsbjT, bsbj, em);
    crf_kernel<<<BB, 64, 0, stream>>>(text, sbj, em, start_t, end_t, trans, acc);
    final_kernel<<<1, 1, 0, stream>>>(acc, out);
}